// Round 15
// baseline (257.866 us; speedup 1.0000x reference)
//
#include <hip/hip_runtime.h>

// LocalCorrRatio on (1,1,90,90,90) fp32. 1000 patches (9x9x9), 32 Parzen bins,
// 4 configs: conf = dir (X/Y swap) x shift (0/4).  out = -(1/12000)*sum eta^2.
//
// R13 = R4 algorithm (exp recurrence: w_{b+1}=w_b*r, r*=e^-2, refresh per
// 8-bin window) but with ALL per-lane arrays replaced by named scalars via
// macro expansion. R12 evidence: VGPR_Count=44 with 48 live floats -> arrays
// were in scratch (private mem), kernel 92% latency-stalled (VALUBusy 7.5%).
// Named scalars force register allocation.

constexpr int   NPATCH = 1000;
constexpr float EM2    = 0.13533528323661270f;   // e^-2

#define FOR11(M) M(0) M(1) M(2) M(3) M(4) M(5) M(6) M(7) M(8) M(9) M(10)
#define FOR12(M) FOR11(M) M(11)

__global__ __launch_bounds__(64)
void cr_patch_kernel(const float* __restrict__ yt,
                     const float* __restrict__ yp,
                     float* __restrict__ partial,    // [4*NPATCH]
                     unsigned* __restrict__ cnt,     // memset 0 per call
                     float* __restrict__ out)
{
    __shared__ float2 lds[32][33];                  // [bin][lane<32], +1 pad

    const int bid  = blockIdx.x;
    const int conf = bid / NPATCH;                  // 0..3
    const int p    = bid - conf * NPATCH;
    const int shift = (conf >= 2) ? 4 : 0;
    const int ph = p / 100, pw = (p / 10) % 10, pd = p % 10;
    const float* __restrict__ X = (conf & 1) ? yp : yt;   // intensity
    const float* __restrict__ Y = (conf & 1) ? yt : yp;   // binned
    const int lane = threadIdx.x;                   // one wave per block

    float sx = 0.f, sx2 = 0.f;

    // ---- 48 named scalars: voxel intensity x_i, scaled bin-coord u_i ----
    #define DECLXU(i) float x##i, u##i;
    FOR12(DECLXU)
    #undef DECLXU

    auto vidx = [&](int j) {
        int dh  = j / 81;
        int rem = j - dh * 81;
        int dw  = rem / 9;
        int dd  = rem - dw * 9;
        int H = ph * 9 + dh + shift; if (H >= 90) H -= 90;
        int W = pw * 9 + dw + shift; if (W >= 90) W -= 90;
        int D = pd * 9 + dd + shift; if (D >= 90) D -= 90;
        return (H * 90 + W) * 90 + D;
    };

    // ---- Load: lane owns voxels j = lane + 64*i (i=0..10), +tail i=11 ----
    #define LOADV(i) { int idx = vidx(lane + (i << 6));                      \
                       x##i = X[idx]; u##i = 31.0f * Y[idx];                 \
                       sx += x##i; sx2 = fmaf(x##i, x##i, sx2); }
    FOR11(LOADV)
    #undef LOADV
    if (lane < 729 - 11 * 64) {                     // lanes 0..24: 12th voxel
        int idx = vidx(lane + 704);
        x11 = X[idx]; u11 = 31.0f * Y[idx];
        sx += x11; sx2 = fmaf(x11, x11, sx2);
    } else {
        x11 = 0.f;                                  // no effect on sums
        u11 = -310.f;                               // w=0, r=exp(-621)=0 (finite)
    }

    #pragma unroll
    for (int m = 1; m < 64; m <<= 1) {
        sx  += __shfl_xor(sx,  m);
        sx2 += __shfl_xor(sx2, m);
    }
    const float mean = sx * (1.0f / 729.0f);

    // ---- Bin sweep: 4 windows x 8 bins, 2-mul recurrence per bin ----
    #define DECLWR(i) float w##i, r##i;
    FOR12(DECLWR)
    #undef DECLWR

    #pragma unroll
    for (int win = 0; win < 4; ++win) {
        const float b0 = (float)(8 * win);
        // refresh: w = exp(-d^2) via (exp(-d^2/2))^2 (underflow-safe),
        //          r = exp(2d-1)  (max exp(61), finite)
        #define REFRESH(i) { float d = u##i - b0;                            \
                             float h = __expf(-0.5f * d * d);                \
                             w##i = h * h;                                   \
                             r##i = __expf(fmaf(2.0f, d, -1.0f)); }
        FOR12(REFRESH)
        #undef REFRESH

        #pragma unroll
        for (int j = 0; j < 8; ++j) {               // bin b = 8*win + j
            float s = 0.f, t = 0.f;
            #define ACC(i) { s += w##i; t = fmaf(w##i, x##i, t);             \
                             w##i *= r##i; r##i *= EM2; }
            FOR12(ACC)
            #undef ACC
            s += __shfl_xor(s, 32);                 // fold upper half-wave
            t += __shfl_xor(t, 32);
            if (lane < 32) lds[8 * win + j][lane] = make_float2(s, t);
        }
    }
    __syncthreads();

    // ---- Transpose-reduce: bin-per-lane over 32 columns ----
    const int b    = lane & 31;
    const int half = lane >> 5;
    float Sw = 0.f, Swx = 0.f;
    #pragma unroll
    for (int l = 0; l < 16; ++l) {
        float2 q = lds[b][half * 16 + l];
        Sw += q.x; Swx += q.y;
    }
    Sw  += __shfl_xor(Sw,  32);
    Swx += __shfl_xor(Swx, 32);

    float mi = Swx / (Sw + 1e-5f);                  // weights_norm denom eps
    float du = mi - mean;
    float tn = Sw * du * du, td = Sw;
    #pragma unroll
    for (int m = 1; m < 32; m <<= 1) {              // reduce 32 bins
        tn += __shfl_xor(tn, m);
        td += __shfl_xor(td, m);
    }

    if (lane == 0) {
        float tv = (sx2 - sx * sx * (1.0f / 729.0f)) * (1.0f / 728.0f);  // ddof=1
        __hip_atomic_store(&partial[bid], (tn / td) / (tv + 1e-5f),
                           __ATOMIC_RELAXED, __HIP_MEMORY_SCOPE_AGENT);
    }

    // ---- Last-block final reduction ----
    __threadfence();
    unsigned old = 0;
    if (lane == 0)
        old = __hip_atomic_fetch_add(cnt, 1u, __ATOMIC_ACQ_REL, __HIP_MEMORY_SCOPE_AGENT);
    old = __shfl(old, 0, 64);
    if (old == 4u * NPATCH - 1u) {
        __threadfence();
        float s = 0.f;
        for (int i = lane; i < 4 * NPATCH; i += 64)
            s += __hip_atomic_load(&partial[i], __ATOMIC_RELAXED, __HIP_MEMORY_SCOPE_AGENT);
        #pragma unroll
        for (int m = 1; m < 64; m <<= 1) s += __shfl_xor(s, m);
        if (lane == 0) out[0] = -s * (1.0f / 12000.0f);
    }
}

extern "C" void kernel_launch(void* const* d_in, const int* in_sizes, int n_in,
                              void* d_out, int out_size, void* d_ws, size_t ws_size,
                              hipStream_t stream)
{
    const float* y_true = (const float*)d_in[0];
    const float* y_pred = (const float*)d_in[1];
    float*    out     = (float*)d_out;
    float*    partial = (float*)d_ws;                    // 4000 floats
    unsigned* cnt     = (unsigned*)((char*)d_ws + 16384);

    hipMemsetAsync(cnt, 0, sizeof(unsigned), stream);
    cr_patch_kernel<<<4 * NPATCH, 64, 0, stream>>>(y_true, y_pred, partial, cnt, out);
}

// Round 17
// 257.491 us; speedup vs baseline: 1.0015x; 1.0015x over previous
//
#include <hip/hip_runtime.h>

// LocalCorrRatio on (1,1,90,90,90) fp32. 1000 patches (9x9x9), 32 Parzen bins,
// 4 configs: conf = dir (X/Y swap) x shift (0/4).  out = -(1/12000)*sum eta^2.
//
// R16 = R13 (named-scalar recurrence sweep) + register-pressure fixes:
//  (1) __launch_bounds__(64, 1): min 1 wave/EU -> allocator may use full VGPR
//      budget instead of spilling to scratch (R12/R15: VGPR=44 < ~48 live
//      floats, 99% latency stall on L2-resident scratch round-trips).
//  (2) outer window loop NOT unrolled (#pragma unroll 1): prevents hoisting
//      of future REFRESH exp blocks, capping peak live values at ~54.

constexpr int   NPATCH = 1000;
constexpr float EM2    = 0.13533528323661270f;   // e^-2

#define FOR11(M) M(0) M(1) M(2) M(3) M(4) M(5) M(6) M(7) M(8) M(9) M(10)
#define FOR12(M) FOR11(M) M(11)

__global__ __launch_bounds__(64, 1)
void cr_patch_kernel(const float* __restrict__ yt,
                     const float* __restrict__ yp,
                     float* __restrict__ partial,    // [4*NPATCH]
                     unsigned* __restrict__ cnt,     // memset 0 per call
                     float* __restrict__ out)
{
    __shared__ float2 lds[32][33];                  // [bin][lane<32], +1 pad

    const int bid  = blockIdx.x;
    const int conf = bid / NPATCH;                  // 0..3
    const int p    = bid - conf * NPATCH;
    const int shift = (conf >= 2) ? 4 : 0;
    const int ph = p / 100, pw = (p / 10) % 10, pd = p % 10;
    const float* __restrict__ X = (conf & 1) ? yp : yt;   // intensity
    const float* __restrict__ Y = (conf & 1) ? yt : yp;   // binned
    const int lane = threadIdx.x;                   // one wave per block

    float sx = 0.f, sx2 = 0.f;

    // ---- 48 named scalars: voxel intensity x_i, scaled bin-coord u_i ----
    #define DECLXU(i) float x##i, u##i;
    FOR12(DECLXU)
    #undef DECLXU

    auto vidx = [&](int j) {
        int dh  = j / 81;
        int rem = j - dh * 81;
        int dw  = rem / 9;
        int dd  = rem - dw * 9;
        int H = ph * 9 + dh + shift; if (H >= 90) H -= 90;
        int W = pw * 9 + dw + shift; if (W >= 90) W -= 90;
        int D = pd * 9 + dd + shift; if (D >= 90) D -= 90;
        return (H * 90 + W) * 90 + D;
    };

    // ---- Load: lane owns voxels j = lane + 64*i (i=0..10), +tail i=11 ----
    #define LOADV(i) { int idx = vidx(lane + (i << 6));                      \
                       x##i = X[idx]; u##i = 31.0f * Y[idx];                 \
                       sx += x##i; sx2 = fmaf(x##i, x##i, sx2); }
    FOR11(LOADV)
    #undef LOADV
    if (lane < 729 - 11 * 64) {                     // lanes 0..24: 12th voxel
        int idx = vidx(lane + 704);
        x11 = X[idx]; u11 = 31.0f * Y[idx];
        sx += x11; sx2 = fmaf(x11, x11, sx2);
    } else {
        x11 = 0.f;                                  // no effect on sums
        u11 = -310.f;                               // w=0, r=exp(-621)=0 (finite)
    }

    #pragma unroll
    for (int m = 1; m < 64; m <<= 1) {
        sx  += __shfl_xor(sx,  m);
        sx2 += __shfl_xor(sx2, m);
    }
    const float mean = sx * (1.0f / 729.0f);

    // ---- Bin sweep: 4 windows x 8 bins, 2-mul recurrence per bin ----
    #define DECLWR(i) float w##i, r##i;
    FOR12(DECLWR)
    #undef DECLWR

    #pragma unroll 1
    for (int win = 0; win < 4; ++win) {             // NOT unrolled: live-range cap
        const float b0 = (float)(8 * win);
        // refresh: w = exp(-d^2) via (exp(-d^2/2))^2 (underflow-safe),
        //          r = exp(2d-1)  (max exp(61), finite)
        #define REFRESH(i) { float d = u##i - b0;                            \
                             float h = __expf(-0.5f * d * d);                \
                             w##i = h * h;                                   \
                             r##i = __expf(fmaf(2.0f, d, -1.0f)); }
        FOR12(REFRESH)
        #undef REFRESH

        #pragma unroll
        for (int j = 0; j < 8; ++j) {               // bin b = 8*win + j
            float s = 0.f, t = 0.f;
            #define ACC(i) { s += w##i; t = fmaf(w##i, x##i, t);             \
                             w##i *= r##i; r##i *= EM2; }
            FOR12(ACC)
            #undef ACC
            s += __shfl_xor(s, 32);                 // fold upper half-wave
            t += __shfl_xor(t, 32);
            if (lane < 32) lds[8 * win + j][lane] = make_float2(s, t);
        }
    }
    __syncthreads();

    // ---- Transpose-reduce: bin-per-lane over 32 columns ----
    const int b    = lane & 31;
    const int half = lane >> 5;
    float Sw = 0.f, Swx = 0.f;
    #pragma unroll
    for (int l = 0; l < 16; ++l) {
        float2 q = lds[b][half * 16 + l];
        Sw += q.x; Swx += q.y;
    }
    Sw  += __shfl_xor(Sw,  32);
    Swx += __shfl_xor(Swx, 32);

    float mi = Swx / (Sw + 1e-5f);                  // weights_norm denom eps
    float du = mi - mean;
    float tn = Sw * du * du, td = Sw;
    #pragma unroll
    for (int m = 1; m < 32; m <<= 1) {              // reduce 32 bins
        tn += __shfl_xor(tn, m);
        td += __shfl_xor(td, m);
    }

    if (lane == 0) {
        float tv = (sx2 - sx * sx * (1.0f / 729.0f)) * (1.0f / 728.0f);  // ddof=1
        __hip_atomic_store(&partial[bid], (tn / td) / (tv + 1e-5f),
                           __ATOMIC_RELAXED, __HIP_MEMORY_SCOPE_AGENT);
    }

    // ---- Last-block final reduction ----
    __threadfence();
    unsigned old = 0;
    if (lane == 0)
        old = __hip_atomic_fetch_add(cnt, 1u, __ATOMIC_ACQ_REL, __HIP_MEMORY_SCOPE_AGENT);
    old = __shfl(old, 0, 64);
    if (old == 4u * NPATCH - 1u) {
        __threadfence();
        float s = 0.f;
        for (int i = lane; i < 4 * NPATCH; i += 64)
            s += __hip_atomic_load(&partial[i], __ATOMIC_RELAXED, __HIP_MEMORY_SCOPE_AGENT);
        #pragma unroll
        for (int m = 1; m < 64; m <<= 1) s += __shfl_xor(s, m);
        if (lane == 0) out[0] = -s * (1.0f / 12000.0f);
    }
}

extern "C" void kernel_launch(void* const* d_in, const int* in_sizes, int n_in,
                              void* d_out, int out_size, void* d_ws, size_t ws_size,
                              hipStream_t stream)
{
    const float* y_true = (const float*)d_in[0];
    const float* y_pred = (const float*)d_in[1];
    float*    out     = (float*)d_out;
    float*    partial = (float*)d_ws;                    // 4000 floats
    unsigned* cnt     = (unsigned*)((char*)d_ws + 16384);

    hipMemsetAsync(cnt, 0, sizeof(unsigned), stream);
    cr_patch_kernel<<<4 * NPATCH, 64, 0, stream>>>(y_true, y_pred, partial, cnt, out);
}

// Round 18
// 99.396 us; speedup vs baseline: 2.5943x; 2.5905x over previous
//
#include <hip/hip_runtime.h>

// LocalCorrRatio on (1,1,90,90,90) fp32. 1000 patches (9x9x9), 32 Parzen bins,
// 4 configs = dir (X/Y swap) x shift (0/4).  out = -(1/12000)*sum eta^2.
//
// R18: spill-proof structure. One 256-thread block per patch. Both shift-sets
// staged in LDS as float2(t,p) (ds_read_b64, 2-addr broadcast). Wave w = conf
// w; lane = (bin, half): each lane streams ~365 voxels for ITS bin: 1 LDS
// read + ~6 VALU (exp2f) per voxel, <=12 live floats -> no scratch possible
// (R12-R17: 48 live floats vs 44 VGPR = ~860 scratch round-trips/wave = 99%
// stall at 204us). Block-wide sums done once in staging.

constexpr int NPATCH = 1000;

__global__ __launch_bounds__(256)
void cr_patch_kernel(const float* __restrict__ yt,
                     const float* __restrict__ yp,
                     float* __restrict__ partial,    // [NPATCH]
                     unsigned* __restrict__ cnt,     // memset 0 per call
                     float* __restrict__ out)
{
    __shared__ float2 sb[2][729];       // [shift-set][voxel] = (t, p)
    __shared__ float  red[4][8];        // per-wave staging sums
    __shared__ float  etas[4];
    __shared__ float  fin1;
    __shared__ float  fred[4];

    const int p   = blockIdx.x;
    const int ph  = p / 100, pw = (p / 10) % 10, pd = p % 10;
    const int tid = threadIdx.x;
    const int wid = tid >> 6, lane = tid & 63;

    // ---- Stage both shift-sets + per-thread partial sums ----
    float a0=0,a1=0,a2=0,a3=0,a4=0,a5=0,a6=0,a7=0;
    for (int j = tid; j < 729; j += 256) {
        int dh = j / 81, rem = j - dh * 81, dw = rem / 9, dd = rem - dw * 9;
        int H0 = ph * 9 + dh, W0 = pw * 9 + dw, D0 = pd * 9 + dd;     // <=89
        int H4 = H0 + 4; if (H4 >= 90) H4 -= 90;
        int W4 = W0 + 4; if (W4 >= 90) W4 -= 90;
        int D4 = D0 + 4; if (D4 >= 90) D4 -= 90;
        int i0 = (H0 * 90 + W0) * 90 + D0;
        int i4 = (H4 * 90 + W4) * 90 + D4;
        float t0 = yt[i0], q0 = yp[i0];
        float t4 = yt[i4], q4 = yp[i4];
        sb[0][j] = make_float2(t0, q0);
        sb[1][j] = make_float2(t4, q4);
        a0 += t0; a1 = fmaf(t0, t0, a1); a2 += q0; a3 = fmaf(q0, q0, a3);
        a4 += t4; a5 = fmaf(t4, t4, a5); a6 += q4; a7 = fmaf(q4, q4, a7);
    }
    #pragma unroll
    for (int m = 1; m < 64; m <<= 1) {
        a0 += __shfl_xor(a0, m); a1 += __shfl_xor(a1, m);
        a2 += __shfl_xor(a2, m); a3 += __shfl_xor(a3, m);
        a4 += __shfl_xor(a4, m); a5 += __shfl_xor(a5, m);
        a6 += __shfl_xor(a6, m); a7 += __shfl_xor(a7, m);
    }
    if (lane == 0) {
        red[wid][0]=a0; red[wid][1]=a1; red[wid][2]=a2; red[wid][3]=a3;
        red[wid][4]=a4; red[wid][5]=a5; red[wid][6]=a6; red[wid][7]=a7;
    }
    __syncthreads();

    // ---- Wave wid == conf: bin-per-lane Parzen sweep ----
    const int conf = wid;
    const int swap = conf & 1;          // 0: x=t (binned p); 1: x=p (binned t)
    const int si   = conf >> 1;         // shift-set
    const int b    = lane & 31, h = lane >> 5;

    float sx = 0.f, sx2 = 0.f;
    #pragma unroll
    for (int wv = 0; wv < 4; ++wv) {
        sx  += red[wv][si * 4 + swap * 2];
        sx2 += red[wv][si * 4 + swap * 2 + 1];
    }
    const float mean = sx * (1.0f / 729.0f);
    const float cb   = (float)b * (1.0f / 31.0f);
    const float KL   = -961.0f * 1.4426950408889634f;   // exp(-961 d^2)=2^(KL d^2)

    float Sw = 0.f, Swx = 0.f;
    const int base = h * 365;           // h=0: 365 voxels, h=1: 364
    if (swap == 0) {
        for (int i = 0; i < 364; ++i) {
            float2 v = sb[si][base + i];
            float d = v.y - cb;
            float w = exp2f(KL * d * d);
            Sw += w; Swx = fmaf(w, v.x, Swx);
        }
        if (h == 0) {
            float2 v = sb[si][364];
            float d = v.y - cb;
            float w = exp2f(KL * d * d);
            Sw += w; Swx = fmaf(w, v.x, Swx);
        }
    } else {
        for (int i = 0; i < 364; ++i) {
            float2 v = sb[si][base + i];
            float d = v.x - cb;
            float w = exp2f(KL * d * d);
            Sw += w; Swx = fmaf(w, v.y, Swx);
        }
        if (h == 0) {
            float2 v = sb[si][364];
            float d = v.x - cb;
            float w = exp2f(KL * d * d);
            Sw += w; Swx = fmaf(w, v.y, Swx);
        }
    }
    // fold the two halves (same bin at lane^32)
    Sw  += __shfl_xor(Sw,  32);
    Swx += __shfl_xor(Swx, 32);

    float mi = Swx / (Sw + 1e-5f);      // weights_norm denom eps
    float du = mi - mean;
    float tn = Sw * du * du, td = Sw;
    #pragma unroll
    for (int m = 1; m < 32; m <<= 1) {  // reduce over 32 bins
        tn += __shfl_xor(tn, m);
        td += __shfl_xor(td, m);
    }
    if (lane == 0) {
        float tv = (sx2 - sx * sx * (1.0f / 729.0f)) * (1.0f / 728.0f);  // ddof=1
        etas[conf] = (tn / td) / (tv + 1e-5f);
    }
    __syncthreads();

    // ---- One result per block; last block reduces ----
    if (tid == 0) {
        partial[p] = etas[0] + etas[1] + etas[2] + etas[3];
        __threadfence();
        unsigned old = atomicAdd(cnt, 1u);
        fin1 = (old == NPATCH - 1) ? 1.f : 0.f;
    }
    __syncthreads();
    if (fin1 != 0.f) {
        __threadfence();
        float s = 0.f;
        for (int i = tid; i < NPATCH; i += 256) s += partial[i];
        #pragma unroll
        for (int m = 1; m < 64; m <<= 1) s += __shfl_xor(s, m);
        if (lane == 0) fred[wid] = s;
        __syncthreads();
        if (tid == 0)
            out[0] = -(fred[0] + fred[1] + fred[2] + fred[3]) * (1.0f / 12000.0f);
    }
}

extern "C" void kernel_launch(void* const* d_in, const int* in_sizes, int n_in,
                              void* d_out, int out_size, void* d_ws, size_t ws_size,
                              hipStream_t stream)
{
    const float* y_true = (const float*)d_in[0];
    const float* y_pred = (const float*)d_in[1];
    float*    out     = (float*)d_out;
    float*    partial = (float*)d_ws;                    // 1000 floats
    unsigned* cnt     = (unsigned*)((char*)d_ws + 8192);

    hipMemsetAsync(cnt, 0, sizeof(unsigned), stream);
    cr_patch_kernel<<<NPATCH, 256, 0, stream>>>(y_true, y_pred, partial, cnt, out);
}